// Round 14
// baseline (254.705 us; speedup 1.0000x reference)
//
#include <hip/hip_runtime.h>
#include <hip/hip_bf16.h>
#include <stdint.h>

#define NODES 50000
#define EDGES 800000
#define DIM 256
#define NREL 8
#define NJ (NREL * DIM)  // 2048 combined output cols (r*256+o)
#define CAP 64           // padded-CSR slots per node (Poisson(16): P(deg>=64)~2e-18)

typedef unsigned short u16;
typedef __attribute__((ext_vector_type(8))) __bf16 bf16x8;
typedef __attribute__((ext_vector_type(8))) unsigned short us8;
typedef __attribute__((ext_vector_type(4))) float f32x4;

#define GLOBAL_AS __attribute__((address_space(1)))
#define LDS_AS __attribute__((address_space(3)))

#define CVT_N4 (NODES * DIM / 4 + NREL * DIM * DIM / 4)  // 3,331,072 = 13012*256
#define CVT_BLKS 13012
#define EDGE_BLKS 3125   // 3125*256 == 800000 exactly
#define GEMM_BLKS 3200   // 8 XCD bands x (25 m-tiles x 16 j-tiles)

__device__ __forceinline__ u16 f2bf(float f) {
  uint32_t u = __builtin_bit_cast(uint32_t, f);
  u += 0x7FFFu + ((u >> 16) & 1u);  // RNE; inputs finite
  return (u16)(u >> 16);
}
__device__ __forceinline__ float bf2f(u16 u) {
  uint32_t t = (uint32_t)u << 16;
  return __builtin_bit_cast(float, t);
}

// ---------------- Tier A (padded CSR + reg-B GEMM) ----------------

// Fused: slot-scatter + used-mask (blocks 0..3124; cnt/mask pre-zeroed by the
// stream-ordered memset) || f32->bf16 convert of x (row-major) and W into the
// fragment-tiled layout wbt[j/16][k/8][16][8] (so the GEMM loads B fragments
// straight from global, fully coalesced, bypassing LDS).
__global__ __launch_bounds__(256) void k_prep_pad(
    const float* __restrict__ x, const float* __restrict__ w,
    u16* __restrict__ xb, u16* __restrict__ wbt,
    const int* __restrict__ esrc, const int* __restrict__ edst,
    const int* __restrict__ et, int* __restrict__ cnt, int* __restrict__ slot,
    unsigned char* __restrict__ mask)
{
  const int b = blockIdx.x;
  if (b < EDGE_BLKS) {
    const int e = b * 256 + threadIdx.x;           // exact coverage of EDGES
    const int d = edst[e];
    const int sgv = esrc[e] * NREL + et[e];        // h row index
    const int p = atomicAdd(&cnt[d], 1);           // ~16-way avg contention
    if (p < CAP) slot[d * CAP + p] = sgv;
    mask[sgv] = 1;                                 // benign write race
    return;
  }
  const int i = (b - EDGE_BLKS) * 256 + threadIdx.x;
  const int n4x = NODES * DIM / 4;
  if (i < n4x) {
    float4 v = ((const float4*)x)[i];
    ushort4 o;
    o.x = f2bf(v.x); o.y = f2bf(v.y); o.z = f2bf(v.z); o.w = f2bf(v.w);
    ((ushort4*)xb)[i] = o;
  } else if (i < CVT_N4) {
    const int j = i - n4x;             // quad index into flat W (f32)
    float4 v = ((const float4*)w)[j];
    ushort4 o;
    o.x = f2bf(v.x); o.y = f2bf(v.y); o.z = f2bf(v.z); o.w = f2bf(v.w);
    const int row = j >> 6;            // combined j-row (r*256+o), 64 quads/row
    const int ii  = (j & 63) * 4;      // k offset 0..252
    // wbt[[row>>4][ii>>3][row&15][ii&7]], dims [128][32][16][8] u16
    u16* dst = wbt + ((size_t)(row >> 4) << 12) + ((ii >> 3) << 7)
                   + ((row & 15) << 3) + (ii & 7);
    *(ushort4*)dst = o;               // 8B-aligned (ii&7 in {0,4}... 4*2=8B ok)
  }
}

// Dense GEMM h = xb @ W^T.  r13 post-mortem: LDS pipe (88KB/K-step) was the
// binding resource (MfmaUtil pinned ~27%).  This round: B fragments load
// DIRECTLY from global (wbt fragment-tiled layout, coalesced 1KB/instr,
// L1/L2-resident weights) — LDS stages A only (48KB/K-step, -45%).
// T4 counted-vmcnt: B(ks) 4 loads + STAGE(ks+1) 2 loads -> vmcnt(2).
// Epilogue skips h rows with mask[row*8+rel]==0 (~13.5% of WRITE).
__global__ __launch_bounds__(512) void k_gemm(
    const u16* __restrict__ xb, const u16* __restrict__ wbt, u16* __restrict__ h,
    const unsigned char* __restrict__ mask)
{
  __shared__ __align__(16) u16 smem[32768];  // 3 x A-buf(8192) | 256x128 epilogue tile

  const int gbid = blockIdx.x;
  const int xcd = gbid & 7;
  const int idx = gbid >> 3;         // 0..399
  const int jg  = idx / 200;         // 0,1
  const int r2  = idx - jg * 200;
  const int m   = xcd * 25 + (r2 >> 3);
  const int mbase = m * 256;
  if (mbase >= NODES) return;
  const int jtile = jg * 8 + (r2 & 7);   // 0..15
  const int jbase = jtile * 128;
  const int rel   = jtile >> 1;          // relation this block's cols belong to

  const int tid = threadIdx.x;
  const int lane = tid & 63;
  const int wv = tid >> 6;           // 0..7
  const int wr = wv >> 1, wc = wv & 1;
  const int swz = (lane & 3) ^ ((lane >> 2) & 3) ^ (lane >> 4);  // 16B-chunk idx

  f32x4 acc[4][4];
#pragma unroll
  for (int mm = 0; mm < 4; ++mm)
#pragma unroll
    for (int n = 0; n < 4; ++n) acc[mm][n] = f32x4{0.f, 0.f, 0.f, 0.f};

  const int arow0 = wv * 32;  // this wave stages A rows [arow0, arow0+32)

  // B per-lane base in wbt: jt = jtile*8 + wc*4 (+n), kt = ks*4 + (lane>>4),
  // elem = (lane&15)*8.  addr(u16) = jt*4096 + kt*128 + (lane&15)*8.
  const u16* bp = wbt + ((size_t)(jtile * 8 + wc * 4) << 12)
                      + ((lane >> 4) << 7) + ((lane & 15) << 3);

  auto STAGE = [&](int buf, int ks) {
    u16* sa = smem + buf * 8192;
#pragma unroll
    for (int c2 = 0; c2 < 2; ++c2) {
      const int rowb = arow0 + c2 * 16;
      const int row  = rowb + (lane >> 2);
      const int ar = min(mbase + row, NODES - 1);  // clamp last tile
      const u16* ga = xb + ((size_t)ar << 8) + (ks << 5) + (swz << 3);
      __builtin_amdgcn_global_load_lds((const GLOBAL_AS uint32_t*)ga,
                                       (LDS_AS uint32_t*)(sa + rowb * 32), 16, 0, 0);
    }
  };

  STAGE(0, 0);  // 2 A-loads in flight
#pragma unroll
  for (int ks = 0; ks < 8; ++ks) {
    bf16x8 bfr[4];
#pragma unroll
    for (int n = 0; n < 4; ++n)
      bfr[n] = *(const bf16x8*)(bp + (n << 12) + (ks << 9));  // coalesced global
    if (ks < 7) {
      STAGE((ks + 1) % 3, ks + 1);                       // +2 A-loads
      asm volatile("s_waitcnt vmcnt(2)" ::: "memory");   // B(ks)+STAGE(ks) landed
    } else {
      asm volatile("s_waitcnt vmcnt(0)" ::: "memory");
    }
    __builtin_amdgcn_s_barrier();

    const u16* sa = smem + (ks % 3) * 8192;
    bf16x8 af[4];
#pragma unroll
    for (int mm = 0; mm < 4; ++mm)
      af[mm] = *(const bf16x8*)(sa + (wr * 64 + mm * 16 + (lane & 15)) * 32 + swz * 8);
#pragma unroll
    for (int mm = 0; mm < 4; ++mm)
#pragma unroll
      for (int n = 0; n < 4; ++n)
        acc[mm][n] = __builtin_amdgcn_mfma_f32_16x16x32_bf16(af[mm], bfr[n], acc[mm][n], 0, 0, 0);
  }
  __syncthreads();  // all waves done reading A bufs before tile overwrite

  // Epilogue: acc -> 256x128 LDS tile, then coalesced 16B stores of USED rows.
  u16* tile = smem;  // 256x128 u16 = 64KB
#pragma unroll
  for (int mm = 0; mm < 4; ++mm) {
#pragma unroll
    for (int q = 0; q < 4; ++q) {
      const int rt = wr * 64 + mm * 16 + (lane >> 4) * 4 + q;
      const int key = ((rt >> 2) & 3) << 4;
#pragma unroll
      for (int n = 0; n < 4; ++n) {
        const int ct = wc * 64 + n * 16 + (lane & 15);
        tile[rt * 128 + (ct ^ key)] = f2bf(acc[mm][n][q]);
      }
    }
  }
  __syncthreads();
#pragma unroll
  for (int i = 0; i < 8; ++i) {
    const int c = tid + i * 512;
    const int row = c >> 4, chunk = c & 15;
    const int grow = mbase + row;
    if (grow < NODES && mask[grow * 8 + rel]) {
      const int key = ((row >> 2) & 3) << 4;
      const us8 v = *(const us8*)(tile + row * 128 + ((chunk * 8) ^ key));
      *((us8*)(h + (size_t)grow * NJ + jbase) + chunk) = v;
    }
  }
}

// Two dst nodes per wave (32 lanes x ushort8 = 512B row), padded slots,
// 8-deep gather ILP (L3-BW-bound per r13; kept as-is).
__global__ __launch_bounds__(256) void k_reduce_pad(
    const u16* __restrict__ h, const int* __restrict__ cnt,
    const int* __restrict__ slot, const float* __restrict__ bias,
    float* __restrict__ out)
{
  const int gw = (int)((blockIdx.x * blockDim.x + threadIdx.x) >> 6);
  const int node = gw * 2 + ((threadIdx.x >> 5) & 1);
  if (node >= NODES) return;
  const int l = threadIdx.x & 31;
  const int lo = node * CAP;
  const int hi = lo + min(cnt[node], CAP);
  const u16* hb = h + l * 8;

  float a[8] = {0.f, 0.f, 0.f, 0.f, 0.f, 0.f, 0.f, 0.f};
  int e = lo;
  for (; e + 8 <= hi; e += 8) {
    const us8 v0 = *(const us8*)(hb + ((size_t)slot[e] << 8));
    const us8 v1 = *(const us8*)(hb + ((size_t)slot[e + 1] << 8));
    const us8 v2 = *(const us8*)(hb + ((size_t)slot[e + 2] << 8));
    const us8 v3 = *(const us8*)(hb + ((size_t)slot[e + 3] << 8));
    const us8 v4 = *(const us8*)(hb + ((size_t)slot[e + 4] << 8));
    const us8 v5 = *(const us8*)(hb + ((size_t)slot[e + 5] << 8));
    const us8 v6 = *(const us8*)(hb + ((size_t)slot[e + 6] << 8));
    const us8 v7 = *(const us8*)(hb + ((size_t)slot[e + 7] << 8));
#pragma unroll
    for (int j = 0; j < 8; ++j)
      a[j] += ((bf2f(v0[j]) + bf2f(v1[j])) + (bf2f(v2[j]) + bf2f(v3[j]))) +
              ((bf2f(v4[j]) + bf2f(v5[j])) + (bf2f(v6[j]) + bf2f(v7[j])));
  }
  for (; e + 2 <= hi; e += 2) {
    const us8 v0 = *(const us8*)(hb + ((size_t)slot[e] << 8));
    const us8 v1 = *(const us8*)(hb + ((size_t)slot[e + 1] << 8));
#pragma unroll
    for (int j = 0; j < 8; ++j) a[j] += bf2f(v0[j]) + bf2f(v1[j]);
  }
  if (e < hi) {
    const us8 v = *(const us8*)(hb + ((size_t)slot[e] << 8));
#pragma unroll
    for (int j = 0; j < 8; ++j) a[j] += bf2f(v[j]);
  }
  const float4 b0 = ((const float4*)bias)[l * 2];
  const float4 b1 = ((const float4*)bias)[l * 2 + 1];
  f32x4 o0 = {a[0] + b0.x, a[1] + b0.y, a[2] + b0.z, a[3] + b0.w};
  f32x4 o1 = {a[4] + b1.x, a[5] + b1.y, a[6] + b1.z, a[7] + b1.w};
  f32x4* op = (f32x4*)(out + (size_t)node * DIM) + l * 2;
  __builtin_nontemporal_store(o0, op);
  __builtin_nontemporal_store(o1, op + 1);
}

// ---------------- Tier C fallback (correctness-only) ----------------

__global__ void k_init_out(float* __restrict__ out, const float* __restrict__ bias) {
  int i = blockIdx.x * blockDim.x + threadIdx.x;
  ((float4*)out)[i] = ((const float4*)bias)[i & 63];
}
__global__ void k_naive(const float* __restrict__ x, const float* __restrict__ w,
                        const int* __restrict__ esrc, const int* __restrict__ edst,
                        const int* __restrict__ et, float* __restrict__ out)
{
  const int lane = threadIdx.x & 63;
  int gw = (blockIdx.x * blockDim.x + threadIdx.x) >> 6;
  const int nw = (gridDim.x * blockDim.x) >> 6;
  for (int e = gw; e < EDGES; e += nw) {
    const int s = esrc[e], d = edst[e], r = et[e];
    const float* xr = x + (size_t)s * DIM;
    const float* wr0 = w + (size_t)r * DIM * DIM;
    float a[4] = {0.f, 0.f, 0.f, 0.f};
    for (int i = 0; i < DIM; ++i) {
      const float xv = xr[i];
#pragma unroll
      for (int c = 0; c < 4; ++c) a[c] += xv * wr0[(size_t)(lane + c * 64) * DIM + i];
    }
#pragma unroll
    for (int c = 0; c < 4; ++c) atomicAdd(&out[(size_t)d * DIM + lane + c * 64], a[c]);
  }
}

extern "C" void kernel_launch(void* const* d_in, const int* in_sizes, int n_in,
                              void* d_out, int out_size, void* d_ws, size_t ws_size,
                              hipStream_t stream) {
  const float* x    = (const float*)d_in[0];
  const float* w    = (const float*)d_in[1];
  const float* bias = (const float*)d_in[2];
  const int* eidx   = (const int*)d_in[3];
  const int* et     = (const int*)d_in[4];
  const int* esrc = eidx;
  const int* edst = eidx + EDGES;
  float* out = (float*)d_out;

  auto pad = [](size_t v) { return (v + 255) & ~(size_t)255; };

  // Tier A layout (cnt and mask adjacent: one memset covers both)
  size_t needA = 0;
  const size_t a_xb = needA;   needA = pad(needA + (size_t)NODES * DIM * 2);
  const size_t a_wbt = needA;  needA = pad(needA + (size_t)NREL * DIM * DIM * 2);
  const size_t a_h  = needA;   needA = pad(needA + (size_t)NODES * NJ * 2);
  const size_t a_cnt = needA;  needA = pad(needA + (size_t)NODES * 4);
  const size_t a_mask = needA; needA = pad(needA + (size_t)NODES * NREL);
  const size_t a_slot = needA; needA = pad(needA + (size_t)NODES * CAP * 4);

  char* ws = (char*)d_ws;
  if (needA <= ws_size) {
    u16* xb  = (u16*)(ws + a_xb);
    u16* wbt = (u16*)(ws + a_wbt);
    u16* h   = (u16*)(ws + a_h);
    int* cnt = (int*)(ws + a_cnt);
    unsigned char* mask = (unsigned char*)(ws + a_mask);
    int* slot = (int*)(ws + a_slot);

    (void)hipMemsetAsync(cnt, 0, a_slot - a_cnt, stream);  // cnt + mask
    k_prep_pad<<<EDGE_BLKS + CVT_BLKS, 256, 0, stream>>>(
        x, w, xb, wbt, esrc, edst, et, cnt, slot, mask);
    k_gemm<<<GEMM_BLKS, 512, 0, stream>>>(xb, wbt, h, mask);
    k_reduce_pad<<<(NODES / 2 * 64 + 255) / 256, 256, 0, stream>>>(h, cnt, slot, bias, out);
  } else {
    k_init_out<<<12500, 256, 0, stream>>>(out, bias);
    k_naive<<<2048, 256, 0, stream>>>(x, w, esrc, edst, et, out);
  }
}

// Round 15
// 200.105 us; speedup vs baseline: 1.2729x; 1.2729x over previous
//
#include <hip/hip_runtime.h>
#include <hip/hip_bf16.h>
#include <stdint.h>

#define NODES 50000
#define EDGES 800000
#define DIM 256
#define NREL 8
#define NJ (NREL * DIM)  // 2048 combined output cols (r*256+o)
#define CAP 64           // padded-CSR slots per node (Poisson(16): P(deg>=64)~2e-18)

typedef unsigned short u16;
typedef __attribute__((ext_vector_type(8))) __bf16 bf16x8;
typedef __attribute__((ext_vector_type(8))) unsigned short us8;
typedef __attribute__((ext_vector_type(4))) float f32x4;

#define GLOBAL_AS __attribute__((address_space(1)))
#define LDS_AS __attribute__((address_space(3)))

#define CVT_N4 (NODES * DIM / 4 + NREL * DIM * DIM / 4)  // 3,331,072 = 13012*256
#define CVT_BLKS 13012
#define EDGE_BLKS 3125   // 3125*256 == 800000 exactly
#define GEMM_BLKS 3200   // 8 XCD bands x (25 m-tiles x 16 j-tiles)

__device__ __forceinline__ u16 f2bf(float f) {
  uint32_t u = __builtin_bit_cast(uint32_t, f);
  u += 0x7FFFu + ((u >> 16) & 1u);  // RNE; inputs finite
  return (u16)(u >> 16);
}
__device__ __forceinline__ float bf2f(u16 u) {
  uint32_t t = (uint32_t)u << 16;
  return __builtin_bit_cast(float, t);
}

// ---------------- Tier A (padded CSR) ----------------

// Fused: slot-scatter + used-mask (blocks 0..3124; cnt/mask pre-zeroed by the
// stream-ordered memset) || f32->bf16 convert of x,w (row-major; r14's
// global-B fragment layout REVERTED — B slice 64KB > 32KB L1, thrashed at
// ~56 B/clk/CU vs LDS 256 B/clk -> gemm 78->132us).
__global__ __launch_bounds__(256) void k_prep_pad(
    const float* __restrict__ x, const float* __restrict__ w,
    u16* __restrict__ xb, u16* __restrict__ wb,
    const int* __restrict__ esrc, const int* __restrict__ edst,
    const int* __restrict__ et, int* __restrict__ cnt, int* __restrict__ slot,
    unsigned char* __restrict__ mask)
{
  const int b = blockIdx.x;
  if (b < EDGE_BLKS) {
    const int e = b * 256 + threadIdx.x;           // exact coverage of EDGES
    const int d = edst[e];
    const int sgv = esrc[e] * NREL + et[e];        // h row index
    const int p = atomicAdd(&cnt[d], 1);           // ~16-way avg contention
    if (p < CAP) slot[d * CAP + p] = sgv;
    mask[sgv] = 1;                                 // benign write race
    return;
  }
  const int i = (b - EDGE_BLKS) * 256 + threadIdx.x;
  const int n4x = NODES * DIM / 4;
  if (i < n4x) {
    float4 v = ((const float4*)x)[i];
    ushort4 o;
    o.x = f2bf(v.x); o.y = f2bf(v.y); o.z = f2bf(v.z); o.w = f2bf(v.w);
    ((ushort4*)xb)[i] = o;
  } else if (i < CVT_N4) {
    const int j = i - n4x;
    float4 v = ((const float4*)w)[j];
    ushort4 o;
    o.x = f2bf(v.x); o.y = f2bf(v.y); o.z = f2bf(v.z); o.w = f2bf(v.w);
    ((ushort4*)wb)[j] = o;
  }
}

// Dense GEMM h = xb @ wb^T (r13 structure: A+B LDS-staged, 3-buffer T4
// counted-vmcnt pipeline, XOR-swizzled staging, LDS-transpose epilogue)
// + r14's PROVEN mask-gated store skip (WRITE 200000->172730 KB).
__global__ __launch_bounds__(512) void k_gemm(
    const u16* __restrict__ xb, const u16* __restrict__ wb, u16* __restrict__ h,
    const unsigned char* __restrict__ mask)
{
  __shared__ __align__(16) u16 smem[36864];  // 3 x [A 8192 | B 4096] u16

  const int gbid = blockIdx.x;
  const int xcd = gbid & 7;
  const int idx = gbid >> 3;         // 0..399
  const int jg  = idx / 200;         // 0,1
  const int r2  = idx - jg * 200;
  const int m   = xcd * 25 + (r2 >> 3);
  const int mbase = m * 256;
  if (mbase >= NODES) return;
  const int jtile = jg * 8 + (r2 & 7);   // 0..15
  const int jbase = jtile * 128;
  const int rel   = jtile >> 1;          // relation this block's cols belong to

  const int tid = threadIdx.x;
  const int lane = tid & 63;
  const int wv = tid >> 6;           // 0..7
  const int wr = wv >> 1, wc = wv & 1;
  const int swz = (lane & 3) ^ ((lane >> 2) & 3) ^ (lane >> 4);  // 16B-chunk idx

  f32x4 acc[4][4];
#pragma unroll
  for (int mm = 0; mm < 4; ++mm)
#pragma unroll
    for (int n = 0; n < 4; ++n) acc[mm][n] = f32x4{0.f, 0.f, 0.f, 0.f};

  const int arow0 = wv * 32;  // this wave stages A rows [arow0, arow0+32)
  const int brow0 = wv * 16;  // and B rows [brow0, brow0+16)

  auto STAGE = [&](int buf, int ks) {
    u16* sa = smem + buf * 12288;
    u16* sb = sa + 8192;
#pragma unroll
    for (int c2 = 0; c2 < 2; ++c2) {
      const int rowb = arow0 + c2 * 16;
      const int row  = rowb + (lane >> 2);
      const int ar = min(mbase + row, NODES - 1);  // clamp last tile
      const u16* ga = xb + ((size_t)ar << 8) + (ks << 5) + (swz << 3);
      __builtin_amdgcn_global_load_lds((const GLOBAL_AS uint32_t*)ga,
                                       (LDS_AS uint32_t*)(sa + rowb * 32), 16, 0, 0);
    }
    const int brow = brow0 + (lane >> 2);
    const u16* gb = wb + ((size_t)(jbase + brow) << 8) + (ks << 5) + (swz << 3);
    __builtin_amdgcn_global_load_lds((const GLOBAL_AS uint32_t*)gb,
                                     (LDS_AS uint32_t*)(sb + brow0 * 32), 16, 0, 0);
  };

  STAGE(0, 0);  // 3 loads in flight
#pragma unroll
  for (int ks = 0; ks < 8; ++ks) {
    if (ks < 7) {
      STAGE((ks + 1) % 3, ks + 1);                       // +3 loads (6 in flight)
      asm volatile("s_waitcnt vmcnt(3)" ::: "memory");   // prev stage landed
    } else {
      asm volatile("s_waitcnt vmcnt(0)" ::: "memory");   // final stage landed
    }
    __builtin_amdgcn_s_barrier();                        // no vmcnt(0) drain here

    const u16* sa = smem + (ks % 3) * 12288;
    const u16* sb = sa + 8192;
    bf16x8 af[4], bfr[4];
#pragma unroll
    for (int mm = 0; mm < 4; ++mm)
      af[mm] = *(const bf16x8*)(sa + (wr * 64 + mm * 16 + (lane & 15)) * 32 + swz * 8);
#pragma unroll
    for (int n = 0; n < 4; ++n)
      bfr[n] = *(const bf16x8*)(sb + (wc * 64 + n * 16 + (lane & 15)) * 32 + swz * 8);
#pragma unroll
    for (int mm = 0; mm < 4; ++mm)
#pragma unroll
      for (int n = 0; n < 4; ++n)
        acc[mm][n] = __builtin_amdgcn_mfma_f32_16x16x32_bf16(af[mm], bfr[n], acc[mm][n], 0, 0, 0);
  }
  __syncthreads();  // all waves done reading bufs before tile overwrite

  // Epilogue: acc -> 256x128 LDS tile, then coalesced 16B stores of USED rows.
  u16* tile = smem;  // 256x128 u16 = 64KB
#pragma unroll
  for (int mm = 0; mm < 4; ++mm) {
#pragma unroll
    for (int q = 0; q < 4; ++q) {
      const int rt = wr * 64 + mm * 16 + (lane >> 4) * 4 + q;
      const int key = ((rt >> 2) & 3) << 4;
#pragma unroll
      for (int n = 0; n < 4; ++n) {
        const int ct = wc * 64 + n * 16 + (lane & 15);
        tile[rt * 128 + (ct ^ key)] = f2bf(acc[mm][n][q]);
      }
    }
  }
  __syncthreads();
#pragma unroll
  for (int i = 0; i < 8; ++i) {
    const int c = tid + i * 512;
    const int row = c >> 4, chunk = c & 15;
    const int grow = mbase + row;
    if (grow < NODES && mask[grow * 8 + rel]) {
      const int key = ((row >> 2) & 3) << 4;
      const us8 v = *(const us8*)(tile + row * 128 + ((chunk * 8) ^ key));
      *((us8*)(h + (size_t)grow * NJ + jbase) + chunk) = v;
    }
  }
}

// Two dst nodes per wave (32 lanes x ushort8 = 512B row), padded slots,
// 8-deep gather ILP (L3-BW-bound per r13).
__global__ __launch_bounds__(256) void k_reduce_pad(
    const u16* __restrict__ h, const int* __restrict__ cnt,
    const int* __restrict__ slot, const float* __restrict__ bias,
    float* __restrict__ out)
{
  const int gw = (int)((blockIdx.x * blockDim.x + threadIdx.x) >> 6);
  const int node = gw * 2 + ((threadIdx.x >> 5) & 1);
  if (node >= NODES) return;
  const int l = threadIdx.x & 31;
  const int lo = node * CAP;
  const int hi = lo + min(cnt[node], CAP);
  const u16* hb = h + l * 8;

  float a[8] = {0.f, 0.f, 0.f, 0.f, 0.f, 0.f, 0.f, 0.f};
  int e = lo;
  for (; e + 8 <= hi; e += 8) {
    const us8 v0 = *(const us8*)(hb + ((size_t)slot[e] << 8));
    const us8 v1 = *(const us8*)(hb + ((size_t)slot[e + 1] << 8));
    const us8 v2 = *(const us8*)(hb + ((size_t)slot[e + 2] << 8));
    const us8 v3 = *(const us8*)(hb + ((size_t)slot[e + 3] << 8));
    const us8 v4 = *(const us8*)(hb + ((size_t)slot[e + 4] << 8));
    const us8 v5 = *(const us8*)(hb + ((size_t)slot[e + 5] << 8));
    const us8 v6 = *(const us8*)(hb + ((size_t)slot[e + 6] << 8));
    const us8 v7 = *(const us8*)(hb + ((size_t)slot[e + 7] << 8));
#pragma unroll
    for (int j = 0; j < 8; ++j)
      a[j] += ((bf2f(v0[j]) + bf2f(v1[j])) + (bf2f(v2[j]) + bf2f(v3[j]))) +
              ((bf2f(v4[j]) + bf2f(v5[j])) + (bf2f(v6[j]) + bf2f(v7[j])));
  }
  for (; e + 2 <= hi; e += 2) {
    const us8 v0 = *(const us8*)(hb + ((size_t)slot[e] << 8));
    const us8 v1 = *(const us8*)(hb + ((size_t)slot[e + 1] << 8));
#pragma unroll
    for (int j = 0; j < 8; ++j) a[j] += bf2f(v0[j]) + bf2f(v1[j]);
  }
  if (e < hi) {
    const us8 v = *(const us8*)(hb + ((size_t)slot[e] << 8));
#pragma unroll
    for (int j = 0; j < 8; ++j) a[j] += bf2f(v[j]);
  }
  const float4 b0 = ((const float4*)bias)[l * 2];
  const float4 b1 = ((const float4*)bias)[l * 2 + 1];
  f32x4 o0 = {a[0] + b0.x, a[1] + b0.y, a[2] + b0.z, a[3] + b0.w};
  f32x4 o1 = {a[4] + b1.x, a[5] + b1.y, a[6] + b1.z, a[7] + b1.w};
  f32x4* op = (f32x4*)(out + (size_t)node * DIM) + l * 2;
  __builtin_nontemporal_store(o0, op);
  __builtin_nontemporal_store(o1, op + 1);
}

// ---------------- Tier C fallback (correctness-only) ----------------

__global__ void k_init_out(float* __restrict__ out, const float* __restrict__ bias) {
  int i = blockIdx.x * blockDim.x + threadIdx.x;
  ((float4*)out)[i] = ((const float4*)bias)[i & 63];
}
__global__ void k_naive(const float* __restrict__ x, const float* __restrict__ w,
                        const int* __restrict__ esrc, const int* __restrict__ edst,
                        const int* __restrict__ et, float* __restrict__ out)
{
  const int lane = threadIdx.x & 63;
  int gw = (blockIdx.x * blockDim.x + threadIdx.x) >> 6;
  const int nw = (gridDim.x * blockDim.x) >> 6;
  for (int e = gw; e < EDGES; e += nw) {
    const int s = esrc[e], d = edst[e], r = et[e];
    const float* xr = x + (size_t)s * DIM;
    const float* wr0 = w + (size_t)r * DIM * DIM;
    float a[4] = {0.f, 0.f, 0.f, 0.f};
    for (int i = 0; i < DIM; ++i) {
      const float xv = xr[i];
#pragma unroll
      for (int c = 0; c < 4; ++c) a[c] += xv * wr0[(size_t)(lane + c * 64) * DIM + i];
    }
#pragma unroll
    for (int c = 0; c < 4; ++c) atomicAdd(&out[(size_t)d * DIM + lane + c * 64], a[c]);
  }
}

extern "C" void kernel_launch(void* const* d_in, const int* in_sizes, int n_in,
                              void* d_out, int out_size, void* d_ws, size_t ws_size,
                              hipStream_t stream) {
  const float* x    = (const float*)d_in[0];
  const float* w    = (const float*)d_in[1];
  const float* bias = (const float*)d_in[2];
  const int* eidx   = (const int*)d_in[3];
  const int* et     = (const int*)d_in[4];
  const int* esrc = eidx;
  const int* edst = eidx + EDGES;
  float* out = (float*)d_out;

  auto pad = [](size_t v) { return (v + 255) & ~(size_t)255; };

  // Tier A layout (cnt and mask adjacent: one memset covers both)
  size_t needA = 0;
  const size_t a_xb = needA;   needA = pad(needA + (size_t)NODES * DIM * 2);
  const size_t a_wb = needA;   needA = pad(needA + (size_t)NREL * DIM * DIM * 2);
  const size_t a_h  = needA;   needA = pad(needA + (size_t)NODES * NJ * 2);
  const size_t a_cnt = needA;  needA = pad(needA + (size_t)NODES * 4);
  const size_t a_mask = needA; needA = pad(needA + (size_t)NODES * NREL);
  const size_t a_slot = needA; needA = pad(needA + (size_t)NODES * CAP * 4);

  char* ws = (char*)d_ws;
  if (needA <= ws_size) {
    u16* xb  = (u16*)(ws + a_xb);
    u16* wb  = (u16*)(ws + a_wb);
    u16* h   = (u16*)(ws + a_h);
    int* cnt = (int*)(ws + a_cnt);
    unsigned char* mask = (unsigned char*)(ws + a_mask);
    int* slot = (int*)(ws + a_slot);

    (void)hipMemsetAsync(cnt, 0, a_slot - a_cnt, stream);  // cnt + mask
    k_prep_pad<<<EDGE_BLKS + CVT_BLKS, 256, 0, stream>>>(
        x, w, xb, wb, esrc, edst, et, cnt, slot, mask);
    k_gemm<<<GEMM_BLKS, 512, 0, stream>>>(xb, wb, h, mask);
    k_reduce_pad<<<(NODES / 2 * 64 + 255) / 256, 256, 0, stream>>>(h, cnt, slot, bias, out);
  } else {
    k_init_out<<<12500, 256, 0, stream>>>(out, bias);
    k_naive<<<2048, 256, 0, stream>>>(x, w, esrc, edst, et, out);
  }
}

// Round 16
// 194.322 us; speedup vs baseline: 1.3107x; 1.0298x over previous
//
#include <hip/hip_runtime.h>
#include <hip/hip_bf16.h>
#include <stdint.h>

#define NODES 50000
#define EDGES 800000
#define DIM 256
#define NREL 8
#define NJ (NREL * DIM)  // 2048 combined output cols (r*256+o)
#define CAP 64           // padded-CSR slots per node (Poisson(16): P(deg>=64)~2e-18)

typedef unsigned short u16;
typedef __attribute__((ext_vector_type(8))) __bf16 bf16x8;
typedef __attribute__((ext_vector_type(8))) unsigned short us8;
typedef __attribute__((ext_vector_type(4))) float f32x4;

#define GLOBAL_AS __attribute__((address_space(1)))
#define LDS_AS __attribute__((address_space(3)))

#define CVT_N4 (NODES * DIM / 4 + NREL * DIM * DIM / 4)  // 3,331,072 = 13012*256
#define CVT_BLKS 13012
#define EDGE_BLKS 3125   // 3125*256 == 800000 exactly
#define GEMM_BLKS 3200   // 8 XCD bands x (25 m-tiles x 16 j-tiles)

__device__ __forceinline__ u16 f2bf(float f) {
  uint32_t u = __builtin_bit_cast(uint32_t, f);
  u += 0x7FFFu + ((u >> 16) & 1u);  // RNE; inputs finite
  return (u16)(u >> 16);
}
__device__ __forceinline__ float bf2f(u16 u) {
  uint32_t t = (uint32_t)u << 16;
  return __builtin_bit_cast(float, t);
}

// ---------------- Tier A (padded CSR) — exact r13 configuration ----------------
// r15 post-mortem: mask-gated store-skip cut WRITE 14% but gemm time was
// UNCHANGED (not write-bound; LDS pipe binds) while prep's mask scatter cost
// ~5us net.  Reverted to the measured-best r13 shape (194.6us).

// Fused: slot-scatter (blocks 0..3124; cnt pre-zeroed by the stream-ordered
// memset) || f32->bf16 convert of x,w.  Safe fusion class: LDS-free streaming.
__global__ __launch_bounds__(256) void k_prep_pad(
    const float* __restrict__ x, const float* __restrict__ w,
    u16* __restrict__ xb, u16* __restrict__ wb,
    const int* __restrict__ esrc, const int* __restrict__ edst,
    const int* __restrict__ et, int* __restrict__ cnt, int* __restrict__ slot)
{
  const int b = blockIdx.x;
  if (b < EDGE_BLKS) {
    const int e = b * 256 + threadIdx.x;           // exact coverage of EDGES
    const int d = edst[e];
    const int p = atomicAdd(&cnt[d], 1);           // ~16-way avg contention
    if (p < CAP) slot[d * CAP + p] = esrc[e] * NREL + et[e];
    return;
  }
  const int i = (b - EDGE_BLKS) * 256 + threadIdx.x;
  const int n4x = NODES * DIM / 4;
  if (i < n4x) {
    float4 v = ((const float4*)x)[i];
    ushort4 o;
    o.x = f2bf(v.x); o.y = f2bf(v.y); o.z = f2bf(v.z); o.w = f2bf(v.w);
    ((ushort4*)xb)[i] = o;
  } else if (i < CVT_N4) {
    const int j = i - n4x;
    float4 v = ((const float4*)w)[j];
    ushort4 o;
    o.x = f2bf(v.x); o.y = f2bf(v.y); o.z = f2bf(v.z); o.w = f2bf(v.w);
    ((ushort4*)wb)[j] = o;
  }
}

// Dense GEMM h = xb @ wb^T: BM=256 x BN=128, 512 thr / 8 waves (4x2 of 64x64),
// T1 XCD bands (25 m-tiles each), T4 counted-vmcnt 3-buffer pipeline,
// XOR-swizzled staging (both-sides), LDS-transpose coalesced epilogue.
__global__ __launch_bounds__(512) void k_gemm(
    const u16* __restrict__ xb, const u16* __restrict__ wb, u16* __restrict__ h)
{
  __shared__ __align__(16) u16 smem[36864];  // 3 x [A 8192 | B 4096] u16

  const int gbid = blockIdx.x;
  const int xcd = gbid & 7;
  const int idx = gbid >> 3;         // 0..399
  const int jg  = idx / 200;         // 0,1
  const int r2  = idx - jg * 200;
  const int m   = xcd * 25 + (r2 >> 3);
  const int mbase = m * 256;
  if (mbase >= NODES) return;
  const int jbase = (jg * 8 + (r2 & 7)) * 128;

  const int tid = threadIdx.x;
  const int lane = tid & 63;
  const int wv = tid >> 6;           // 0..7
  const int wr = wv >> 1, wc = wv & 1;
  const int swz = (lane & 3) ^ ((lane >> 2) & 3) ^ (lane >> 4);  // 16B-chunk idx

  f32x4 acc[4][4];
#pragma unroll
  for (int mm = 0; mm < 4; ++mm)
#pragma unroll
    for (int n = 0; n < 4; ++n) acc[mm][n] = f32x4{0.f, 0.f, 0.f, 0.f};

  const int arow0 = wv * 32;  // this wave stages A rows [arow0, arow0+32)
  const int brow0 = wv * 16;  // and B rows [brow0, brow0+16)

  auto STAGE = [&](int buf, int ks) {
    u16* sa = smem + buf * 12288;
    u16* sb = sa + 8192;
#pragma unroll
    for (int c2 = 0; c2 < 2; ++c2) {
      const int rowb = arow0 + c2 * 16;
      const int row  = rowb + (lane >> 2);
      const int ar = min(mbase + row, NODES - 1);  // clamp last tile
      const u16* ga = xb + ((size_t)ar << 8) + (ks << 5) + (swz << 3);
      __builtin_amdgcn_global_load_lds((const GLOBAL_AS uint32_t*)ga,
                                       (LDS_AS uint32_t*)(sa + rowb * 32), 16, 0, 0);
    }
    const int brow = brow0 + (lane >> 2);
    const u16* gb = wb + ((size_t)(jbase + brow) << 8) + (ks << 5) + (swz << 3);
    __builtin_amdgcn_global_load_lds((const GLOBAL_AS uint32_t*)gb,
                                     (LDS_AS uint32_t*)(sb + brow0 * 32), 16, 0, 0);
  };

  STAGE(0, 0);  // 3 loads in flight
#pragma unroll
  for (int ks = 0; ks < 8; ++ks) {
    if (ks < 7) {
      STAGE((ks + 1) % 3, ks + 1);                       // +3 loads (6 in flight)
      asm volatile("s_waitcnt vmcnt(3)" ::: "memory");   // prev stage landed
    } else {
      asm volatile("s_waitcnt vmcnt(0)" ::: "memory");   // final stage landed
    }
    __builtin_amdgcn_s_barrier();                        // no vmcnt(0) drain here

    const u16* sa = smem + (ks % 3) * 12288;
    const u16* sb = sa + 8192;
    bf16x8 af[4], bfr[4];
#pragma unroll
    for (int mm = 0; mm < 4; ++mm)
      af[mm] = *(const bf16x8*)(sa + (wr * 64 + mm * 16 + (lane & 15)) * 32 + swz * 8);
#pragma unroll
    for (int n = 0; n < 4; ++n)
      bfr[n] = *(const bf16x8*)(sb + (wc * 64 + n * 16 + (lane & 15)) * 32 + swz * 8);
#pragma unroll
    for (int mm = 0; mm < 4; ++mm)
#pragma unroll
      for (int n = 0; n < 4; ++n)
        acc[mm][n] = __builtin_amdgcn_mfma_f32_16x16x32_bf16(af[mm], bfr[n], acc[mm][n], 0, 0, 0);
  }
  __syncthreads();  // all waves done reading bufs before tile overwrite

  // Epilogue: acc -> 256x128 LDS tile, then coalesced 16B stores.
  u16* tile = smem;  // 256x128 u16 = 64KB
#pragma unroll
  for (int mm = 0; mm < 4; ++mm) {
#pragma unroll
    for (int q = 0; q < 4; ++q) {
      const int rt = wr * 64 + mm * 16 + (lane >> 4) * 4 + q;
      const int key = ((rt >> 2) & 3) << 4;
#pragma unroll
      for (int n = 0; n < 4; ++n) {
        const int ct = wc * 64 + n * 16 + (lane & 15);
        tile[rt * 128 + (ct ^ key)] = f2bf(acc[mm][n][q]);
      }
    }
  }
  __syncthreads();
#pragma unroll
  for (int i = 0; i < 8; ++i) {
    const int c = tid + i * 512;
    const int row = c >> 4, chunk = c & 15;
    const int grow = mbase + row;
    if (grow < NODES) {
      const int key = ((row >> 2) & 3) << 4;
      const us8 v = *(const us8*)(tile + row * 128 + ((chunk * 8) ^ key));
      *((us8*)(h + (size_t)grow * NJ + jbase) + chunk) = v;
    }
  }
}

// Two dst nodes per wave (32 lanes x ushort8 = 512B row), padded slots,
// 8-deep gather ILP (L3-BW-bound per r13).
__global__ __launch_bounds__(256) void k_reduce_pad(
    const u16* __restrict__ h, const int* __restrict__ cnt,
    const int* __restrict__ slot, const float* __restrict__ bias,
    float* __restrict__ out)
{
  const int gw = (int)((blockIdx.x * blockDim.x + threadIdx.x) >> 6);
  const int node = gw * 2 + ((threadIdx.x >> 5) & 1);
  if (node >= NODES) return;
  const int l = threadIdx.x & 31;
  const int lo = node * CAP;
  const int hi = lo + min(cnt[node], CAP);
  const u16* hb = h + l * 8;

  float a[8] = {0.f, 0.f, 0.f, 0.f, 0.f, 0.f, 0.f, 0.f};
  int e = lo;
  for (; e + 8 <= hi; e += 8) {
    const us8 v0 = *(const us8*)(hb + ((size_t)slot[e] << 8));
    const us8 v1 = *(const us8*)(hb + ((size_t)slot[e + 1] << 8));
    const us8 v2 = *(const us8*)(hb + ((size_t)slot[e + 2] << 8));
    const us8 v3 = *(const us8*)(hb + ((size_t)slot[e + 3] << 8));
    const us8 v4 = *(const us8*)(hb + ((size_t)slot[e + 4] << 8));
    const us8 v5 = *(const us8*)(hb + ((size_t)slot[e + 5] << 8));
    const us8 v6 = *(const us8*)(hb + ((size_t)slot[e + 6] << 8));
    const us8 v7 = *(const us8*)(hb + ((size_t)slot[e + 7] << 8));
#pragma unroll
    for (int j = 0; j < 8; ++j)
      a[j] += ((bf2f(v0[j]) + bf2f(v1[j])) + (bf2f(v2[j]) + bf2f(v3[j]))) +
              ((bf2f(v4[j]) + bf2f(v5[j])) + (bf2f(v6[j]) + bf2f(v7[j])));
  }
  for (; e + 2 <= hi; e += 2) {
    const us8 v0 = *(const us8*)(hb + ((size_t)slot[e] << 8));
    const us8 v1 = *(const us8*)(hb + ((size_t)slot[e + 1] << 8));
#pragma unroll
    for (int j = 0; j < 8; ++j) a[j] += bf2f(v0[j]) + bf2f(v1[j]);
  }
  if (e < hi) {
    const us8 v = *(const us8*)(hb + ((size_t)slot[e] << 8));
#pragma unroll
    for (int j = 0; j < 8; ++j) a[j] += bf2f(v[j]);
  }
  const float4 b0 = ((const float4*)bias)[l * 2];
  const float4 b1 = ((const float4*)bias)[l * 2 + 1];
  f32x4 o0 = {a[0] + b0.x, a[1] + b0.y, a[2] + b0.z, a[3] + b0.w};
  f32x4 o1 = {a[4] + b1.x, a[5] + b1.y, a[6] + b1.z, a[7] + b1.w};
  f32x4* op = (f32x4*)(out + (size_t)node * DIM) + l * 2;
  __builtin_nontemporal_store(o0, op);
  __builtin_nontemporal_store(o1, op + 1);
}

// ---------------- Tier C fallback (correctness-only) ----------------

__global__ void k_init_out(float* __restrict__ out, const float* __restrict__ bias) {
  int i = blockIdx.x * blockDim.x + threadIdx.x;
  ((float4*)out)[i] = ((const float4*)bias)[i & 63];
}
__global__ void k_naive(const float* __restrict__ x, const float* __restrict__ w,
                        const int* __restrict__ esrc, const int* __restrict__ edst,
                        const int* __restrict__ et, float* __restrict__ out)
{
  const int lane = threadIdx.x & 63;
  int gw = (blockIdx.x * blockDim.x + threadIdx.x) >> 6;
  const int nw = (gridDim.x * blockDim.x) >> 6;
  for (int e = gw; e < EDGES; e += nw) {
    const int s = esrc[e], d = edst[e], r = et[e];
    const float* xr = x + (size_t)s * DIM;
    const float* wr0 = w + (size_t)r * DIM * DIM;
    float a[4] = {0.f, 0.f, 0.f, 0.f};
    for (int i = 0; i < DIM; ++i) {
      const float xv = xr[i];
#pragma unroll
      for (int c = 0; c < 4; ++c) a[c] += xv * wr0[(size_t)(lane + c * 64) * DIM + i];
    }
#pragma unroll
    for (int c = 0; c < 4; ++c) atomicAdd(&out[(size_t)d * DIM + lane + c * 64], a[c]);
  }
}

extern "C" void kernel_launch(void* const* d_in, const int* in_sizes, int n_in,
                              void* d_out, int out_size, void* d_ws, size_t ws_size,
                              hipStream_t stream) {
  const float* x    = (const float*)d_in[0];
  const float* w    = (const float*)d_in[1];
  const float* bias = (const float*)d_in[2];
  const int* eidx   = (const int*)d_in[3];
  const int* et     = (const int*)d_in[4];
  const int* esrc = eidx;
  const int* edst = eidx + EDGES;
  float* out = (float*)d_out;

  auto pad = [](size_t v) { return (v + 255) & ~(size_t)255; };

  // Tier A layout
  size_t needA = 0;
  const size_t a_xb = needA;   needA = pad(needA + (size_t)NODES * DIM * 2);
  const size_t a_wb = needA;   needA = pad(needA + (size_t)NREL * DIM * DIM * 2);
  const size_t a_h  = needA;   needA = pad(needA + (size_t)NODES * NJ * 2);
  const size_t a_cnt = needA;  needA = pad(needA + (size_t)NODES * 4);
  const size_t a_slot = needA; needA = pad(needA + (size_t)NODES * CAP * 4);

  char* ws = (char*)d_ws;
  if (needA <= ws_size) {
    u16* xb  = (u16*)(ws + a_xb);
    u16* wb  = (u16*)(ws + a_wb);
    u16* h   = (u16*)(ws + a_h);
    int* cnt = (int*)(ws + a_cnt);
    int* slot = (int*)(ws + a_slot);

    (void)hipMemsetAsync(cnt, 0, (size_t)NODES * 4, stream);
    k_prep_pad<<<EDGE_BLKS + CVT_BLKS, 256, 0, stream>>>(
        x, w, xb, wb, esrc, edst, et, cnt, slot);
    k_gemm<<<GEMM_BLKS, 512, 0, stream>>>(xb, wb, h);
    k_reduce_pad<<<(NODES / 2 * 64 + 255) / 256, 256, 0, stream>>>(h, cnt, slot, bias, out);
  } else {
    k_init_out<<<12500, 256, 0, stream>>>(out, bias);
    k_naive<<<2048, 256, 0, stream>>>(x, w, esrc, edst, et, out);
  }
}